// Round 18
// baseline (989.564 us; speedup 1.0000x reference)
//
#include <hip/hip_runtime.h>
#include <hip/hip_bf16.h>

// B=8, C=256, NH=8, DH=32, N=1024 (32x32), L=8, DFF=1025 (pad 1152)
// conv0: fused direct. convs 1-3: halo-LDS direct MFMA. convs 4-7: implicit-GEMM.
// GEMM: BK=64, 3-bit XOR LDS swizzle (pre-swizzled global source), counted-vmcnt
// double-buffer pipeline. k_mlp: 80 uniform 16KB weight stages, ring-3 LDS,
// chunk-fused lin1->lin2 (pch 8.5KB) => 73.5KB LDS => 2 blocks/CU.
// Exact-sparse 7x7 attention.

typedef __bf16 bf16x8 __attribute__((ext_vector_type(8)));
typedef float f32x4 __attribute__((ext_vector_type(4)));
typedef unsigned short us8v __attribute__((ext_vector_type(8)));

__device__ __forceinline__ unsigned short f2bf(float f) {
  unsigned int u = __float_as_uint(f);
  unsigned int r = (u + 0x7fffu + ((u >> 16) & 1u)) >> 16;
  return (unsigned short)r;
}
__device__ __forceinline__ float bf2f(unsigned short h) {
  return __uint_as_float(((unsigned int)h) << 16);
}

#define GLD16(src, dst)                                                        \
  __builtin_amdgcn_global_load_lds(                                            \
      (const __attribute__((address_space(1))) unsigned int*)(src),            \
      (__attribute__((address_space(3))) unsigned int*)(dst), 16, 0, 0)

// ---------------- unified bf16 MFMA GEMM, BK=64, counted-vmcnt pipeline --------
template<int BM, int BN, int NT, int MODE, int LNF = 0, int KTC = 0>
__global__ __launch_bounds__(NT) void k_gemm(
    const unsigned short* __restrict__ A, int lda,
    const unsigned short* __restrict__ Bw, int ldb,
    const float* __restrict__ bias, const float* __restrict__ posadd,
    float* __restrict__ C, unsigned short* __restrict__ Cb, int ldc,
    int K, int Nstore, int act, int omode, long long zsB, long long zsC,
    const unsigned short* __restrict__ zpage, int Ci, int Hi, int stride, int lw,
    int divm, int divs, const float* __restrict__ lng, const float* __restrict__ lnb)
{
  constexpr int NW = NT / 64;
  constexpr int NWN = (NT == 512) ? 4 : ((BN >= 128) ? 2 : 1);
  constexpr int NWM = NW / NWN;
  constexpr int WM = BM / NWM, WN = BN / NWN;
  constexpr int MF = WM / 16, NF = WN / 16;
  constexpr int AIS = (BM * 8) / NT;
  constexpr int BIS = (BN * 8) / NT;
  __shared__ unsigned short lA[2][BM * 64];
  __shared__ unsigned short lB[2][BN * 64];
  int tid = threadIdx.x, lane = tid & 63, wid = tid >> 6;
  int bm = blockIdx.x * BM, bn = blockIdx.y * BN;
  const unsigned short* Bz = Bw + (size_t)blockIdx.z * zsB;

  int j = (lane & 7) ^ (lane >> 3);   // source chunk this lane fetches
  int e8 = (j & 3) << 3;
  int halfl = j >> 2;

  size_t arow[AIS], brow[BIS];
  int hb[AIS], wb[AIS];
  size_t ab[AIS];
#pragma unroll
  for (int i = 0; i < AIS; ++i) {
    int rr = (wid + i * NW) * 8 + (lane >> 3);
    if constexpr (MODE == 0) {
      arow[i] = (size_t)(bm + rr) * lda + (j << 3);
    } else {
      int pos = bm + rr;
      int b = pos >> (2 * lw);
      int rem = pos & ((1 << (2 * lw)) - 1);
      int ho = rem >> lw, wo = rem & ((1 << lw) - 1);
      hb[i] = ho * stride - 1;
      wb[i] = wo * stride - 1;
      ab[i] = (size_t)b * Hi * Hi * Ci;
    }
  }
#pragma unroll
  for (int i = 0; i < BIS; ++i)
    brow[i] = (size_t)(bn + (wid + i * NW) * 8 + (lane >> 3)) * ldb + (j << 3);

  auto stage = [&](int buf, int kt) {
    if constexpr (MODE == 1) {
      int s0 = kt * 2, s1 = s0 + 1;
      int t0 = (s0 * divm) >> divs, t1 = (s1 * divm) >> divs;
      int cipw = Ci >> 5;
      int cc0 = (s0 - t0 * cipw) << 5, cc1 = (s1 - t1 * cipw) << 5;
      int kh0 = (t0 * 171) >> 9, kw0 = t0 - kh0 * 3;
      int kh1 = (t1 * 171) >> 9, kw1 = t1 - kh1 * 3;
      int kh = halfl ? kh1 : kh0;
      int kw = halfl ? kw1 : kw0;
      int cco = halfl ? cc1 : cc0;
      bool tv = (halfl ? t1 : t0) < 9;
#pragma unroll
      for (int i = 0; i < AIS; ++i) {
        int hi = hb[i] + kh, wi = wb[i] + kw;
        const unsigned short* ap =
            (tv && (unsigned)hi < (unsigned)Hi && (unsigned)wi < (unsigned)Hi)
                ? (A + ab[i] + (size_t)(hi * Hi + wi) * Ci + cco + e8)
                : zpage;
        GLD16(ap, &lA[buf][(wid + i * NW) * 512]);
      }
    } else {
#pragma unroll
      for (int i = 0; i < AIS; ++i)
        GLD16(A + arow[i] + kt * 64, &lA[buf][(wid + i * NW) * 512]);
    }
#pragma unroll
    for (int i = 0; i < BIS; ++i)
      GLD16(Bz + brow[i] + kt * 64, &lB[buf][(wid + i * NW) * 512]);
  };

  f32x4 acc[MF][NF];
#pragma unroll
  for (int m = 0; m < MF; ++m)
#pragma unroll
    for (int n = 0; n < NF; ++n)
#pragma unroll
      for (int q = 0; q < 4; ++q) acc[m][n][q] = 0.f;

  int wn = wid % NWN, wm = wid / NWN;
  int r0 = wm * WM + (lane & 15);
  int c0 = wn * WN + (lane & 15);
  int sl0 = (((lane >> 4)) ^ (lane & 7)) << 3;
  int sl1 = (((lane >> 4) + 4) ^ (lane & 7)) << 3;
  const int nkt = (KTC > 0) ? KTC : (K >> 6);
  int cur = 0;
  stage(0, 0);
#pragma unroll
  for (int kt = 0; kt < nkt; ++kt) {
    if (kt + 1 < nkt) {
      stage(cur ^ 1, kt + 1);
      asm volatile("s_waitcnt vmcnt(%0)" : : "n"(AIS + BIS) : "memory");
    } else {
      asm volatile("s_waitcnt vmcnt(0)" : : : "memory");
    }
    __builtin_amdgcn_s_barrier();
    asm volatile("" ::: "memory");
    bf16x8 a0[MF], a1[MF], b0[NF], b1[NF];
#pragma unroll
    for (int m = 0; m < MF; ++m) {
      a0[m] = *(const bf16x8*)&lA[cur][(r0 + m * 16) * 64 + sl0];
      a1[m] = *(const bf16x8*)&lA[cur][(r0 + m * 16) * 64 + sl1];
    }
#pragma unroll
    for (int n = 0; n < NF; ++n) {
      b0[n] = *(const bf16x8*)&lB[cur][(c0 + n * 16) * 64 + sl0];
      b1[n] = *(const bf16x8*)&lB[cur][(c0 + n * 16) * 64 + sl1];
    }
#pragma unroll
    for (int m = 0; m < MF; ++m)
#pragma unroll
      for (int n = 0; n < NF; ++n)
        acc[m][n] = __builtin_amdgcn_mfma_f32_16x16x32_bf16(a0[m], b0[n], acc[m][n], 0, 0, 0);
#pragma unroll
    for (int m = 0; m < MF; ++m)
#pragma unroll
      for (int n = 0; n < NF; ++n)
        acc[m][n] = __builtin_amdgcn_mfma_f32_16x16x32_bf16(a1[m], b1[n], acc[m][n], 0, 0, 0);
    asm volatile("" ::: "memory");
    __builtin_amdgcn_s_barrier();
    cur ^= 1;
  }

  int colb = bn + wn * WN + (lane & 15);
  int rowb = bm + wm * WM + ((lane >> 4) << 2);
  float* Cz = C ? C + (size_t)blockIdx.z * zsC : nullptr;
  unsigned short* Cbz = Cb ? Cb + (size_t)blockIdx.z * zsC : nullptr;
#pragma unroll
  for (int n = 0; n < NF; ++n) {
    int col = colb + n * 16;
    if (col >= Nstore) continue;
    float bs = bias ? bias[col] : 0.f;
#pragma unroll
    for (int m = 0; m < MF; ++m) {
#pragma unroll
      for (int q = 0; q < 4; ++q) {
        int row = rowb + m * 16 + q;
        float v = acc[m][n][q] + bs;
        if (posadd && col < 512) v += posadd[((row & 1023) << 9) + col];
        if (act == 1) v = fmaxf(v, 0.f);
        else if (act == 2) v = v / (1.f + __expf(-v));
        size_t off = (size_t)row * ldc + col;
        if (omode == 0) Cz[off] = v;
        else if (omode == 1) Cbz[off] = f2bf(v);
        else { Cz[off] = v; Cbz[off] = f2bf(v); }
      }
    }
  }
}

// ---------------- fused layer tail: 80-stage ring-3 pipeline, 2 blocks/CU -------
// Block = 32 rows, 4 waves (2M x 2N). Stage = 16KB = [128 w-rows][64 k] bf16.
// Stages: 0-7 outproj; then per ny (9): 4 W1 stages -> pch chunk (relu), then
// 4 W2 stages consume pch into acc2. k-order per accumulator identical to the
// unfused version. LDS 73.5KB => 2 blocks/CU.
__global__ __launch_bounds__(256) void k_mlp(
    const unsigned short* __restrict__ ctx, const unsigned short* __restrict__ wo,
    const float* __restrict__ ob,
    const unsigned short* __restrict__ w1, const float* __restrict__ b1,
    const unsigned short* __restrict__ w2, const float* __restrict__ b2,
    float* __restrict__ src, unsigned short* __restrict__ sbo,
    const float* __restrict__ g1, const float* __restrict__ lb1,
    const float* __restrict__ g2, const float* __restrict__ lb2)
{
  __shared__ unsigned short aT[4][32 * 64];      // 16 KB
  __shared__ unsigned short lB[3][128 * 64];     // 48 KB ring
  __shared__ unsigned short pch[32][136];        // 8.5 KB (stride 272B: 16B-aligned, 2-way)
  __shared__ float red[2][32][2];                // 1 KB
  int tid = threadIdx.x, lane = tid & 63, wid = tid >> 6;
  int bm = blockIdx.x << 5;
  int rsrc = lane >> 3;
  int jj8 = ((lane & 7) ^ rsrc) << 3;

  // stage A (ctx): 4 k-tiles (issued first -> completed by first vmcnt(4) waits)
  {
    int rr = wid * 8 + rsrc;
    const unsigned short* ap = ctx + (size_t)(bm + rr) * 256 + jj8;
#pragma unroll
    for (int kt = 0; kt < 4; ++kt)
      GLD16(ap + kt * 64, &aT[kt][wid * 512]);
  }
  asm volatile("s_waitcnt vmcnt(0)" ::: "memory");   // drain A-stage before ring

  // linear weight-stage issue, s in [0,80)
  auto issue = [&](int s) {
    const unsigned short* base;
    int ld, coloff, row0;
    if (s < 8)  { base = wo; ld = 256; coloff = (s >> 1) * 64; row0 = (s & 1) * 128; }
    else {
      int t = s - 8, ny = t >> 3, u = t & 7;
      if (u < 4) { base = w1; ld = 256;  row0 = ny * 128; coloff = u * 64; }
      else { int v = u - 4; base = w2; ld = 1152; row0 = (v & 1) * 128; coloff = ny * 128 + (v >> 1) * 64; }
    }
    int buf = s % 3;
#pragma unroll
    for (int i = 0; i < 4; ++i) {
      int rr = row0 + (wid + i * 4) * 8 + rsrc;
      GLD16(base + (size_t)rr * ld + coloff + jj8, &lB[buf][(wid + i * 4) * 512]);
    }
  };
  issue(0); issue(1);

  int wn = wid & 1, wm = wid >> 1;
  int r0 = wm * 16 + (lane & 15);
  int sl0 = ((lane >> 4) ^ (lane & 7)) << 3;
  int sl1 = (((lane >> 4) + 4) ^ (lane & 7)) << 3;
  int kqa = (lane >> 4) << 3;
  int cbase = wn * 16 + (lane & 15);              // frag col base within 128-half
  int rowl = wm * 16 + ((lane >> 4) << 2);

  auto stage_top = [&](int s) {
    if (s == 79) { asm volatile("s_waitcnt vmcnt(0)" ::: "memory"); }
    else         { asm volatile("s_waitcnt vmcnt(4)" ::: "memory"); }
    __builtin_amdgcn_s_barrier();
    asm volatile("" ::: "memory");
    if (s + 2 < 80) issue(s + 2);
  };

  // ---- phase A: out-proj, stages 0..7 ----
  f32x4 acco[8];
#pragma unroll
  for (int m = 0; m < 8; ++m)
#pragma unroll
    for (int q = 0; q < 4; ++q) acco[m][q] = 0.f;
#pragma unroll
  for (int s = 0; s < 8; ++s) {
    const int kt = s >> 1, rh = s & 1;
    stage_top(s);
    bf16x8 a0 = *(const bf16x8*)&aT[kt][r0 * 64 + sl0];
    bf16x8 a1 = *(const bf16x8*)&aT[kt][r0 * 64 + sl1];
    bf16x8 b0v[4], b1v[4];
#pragma unroll
    for (int nn = 0; nn < 4; ++nn) {
      int rowb = cbase + nn * 32;
      b0v[nn] = *(const bf16x8*)&lB[s % 3][rowb * 64 + sl0];
      b1v[nn] = *(const bf16x8*)&lB[s % 3][rowb * 64 + sl1];
    }
    __builtin_amdgcn_s_setprio(1);
#pragma unroll
    for (int nn = 0; nn < 4; ++nn)
      acco[rh * 4 + nn] = __builtin_amdgcn_mfma_f32_16x16x32_bf16(a0, b0v[nn], acco[rh * 4 + nn], 0, 0, 0);
#pragma unroll
    for (int nn = 0; nn < 4; ++nn)
      acco[rh * 4 + nn] = __builtin_amdgcn_mfma_f32_16x16x32_bf16(a1, b1v[nn], acco[rh * 4 + nn], 0, 0, 0);
    __builtin_amdgcn_s_setprio(0);
    asm volatile("" ::: "memory");
    __builtin_amdgcn_s_barrier();
  }

  // ---- add + LN1 -> resid regs + aT (swizzled bf16); stages 8,9 stay in flight --
  float resid[8][4];
  {
    float x[8][4];
    float sums[4] = {0.f, 0.f, 0.f, 0.f}, sqs[4] = {0.f, 0.f, 0.f, 0.f};
#pragma unroll
    for (int m = 0; m < 8; ++m) {
      int col = ((m >> 2) << 7) + cbase + ((m & 3) << 5);
      float bs = ob[col];
#pragma unroll
      for (int q = 0; q < 4; ++q) {
        float v = acco[m][q] + bs + src[(size_t)(bm + rowl + q) * 256 + col];
        x[m][q] = v;
        sums[q] += v;
        sqs[q] += v * v;
      }
    }
#pragma unroll
    for (int q = 0; q < 4; ++q) {
      sums[q] += __shfl_xor(sums[q], 1); sqs[q] += __shfl_xor(sqs[q], 1);
      sums[q] += __shfl_xor(sums[q], 2); sqs[q] += __shfl_xor(sqs[q], 2);
      sums[q] += __shfl_xor(sums[q], 4); sqs[q] += __shfl_xor(sqs[q], 4);
      sums[q] += __shfl_xor(sums[q], 8); sqs[q] += __shfl_xor(sqs[q], 8);
    }
    if ((lane & 15) == 0) {
#pragma unroll
      for (int q = 0; q < 4; ++q) {
        red[wn][rowl + q][0] = sums[q];
        red[wn][rowl + q][1] = sqs[q];
      }
    }
    asm volatile("s_waitcnt lgkmcnt(0)" ::: "memory");
    __builtin_amdgcn_s_barrier();
    asm volatile("" ::: "memory");
#pragma unroll
    for (int q = 0; q < 4; ++q) {
      float ts = sums[q] + red[wn ^ 1][rowl + q][0];
      float tq = sqs[q] + red[wn ^ 1][rowl + q][1];
      float mu = ts * (1.f / 256.f);
      float var = tq * (1.f / 256.f) - mu * mu;
      float rs = rsqrtf(var + 1e-5f);
      int r = rowl + q;
#pragma unroll
      for (int m = 0; m < 8; ++m) {
        int col = ((m >> 2) << 7) + cbase + ((m & 3) << 5);
        float o = (x[m][q] - mu) * rs * g1[col] + lb1[col];
        resid[m][q] = o;
        int kt = col >> 6, jjc = (col >> 3) & 7, e = col & 7;
        aT[kt][r * 64 + ((jjc ^ (r & 7)) << 3) + e] = f2bf(o);
      }
    }
  }
  asm volatile("s_waitcnt lgkmcnt(0)" ::: "memory");
  __builtin_amdgcn_s_barrier();
  asm volatile("" ::: "memory");

  // ---- phases B+C interleaved per ny: 4 lin1 stages -> pch, 4 lin2 stages ------
  f32x4 acc2[8];
#pragma unroll
  for (int m = 0; m < 8; ++m)
#pragma unroll
    for (int q = 0; q < 4; ++q) acc2[m][q] = 0.f;

  for (int ny = 0; ny < 9; ++ny) {
    // lin1: 4 k-tiles into acc1
    f32x4 acc1[4];
#pragma unroll
    for (int nn = 0; nn < 4; ++nn)
#pragma unroll
      for (int q = 0; q < 4; ++q) acc1[nn][q] = 0.f;
#pragma unroll
    for (int u = 0; u < 4; ++u) {
      int s = 8 + ny * 8 + u;
      stage_top(s);
      bf16x8 a0 = *(const bf16x8*)&aT[u][r0 * 64 + sl0];
      bf16x8 a1 = *(const bf16x8*)&aT[u][r0 * 64 + sl1];
      bf16x8 b0v[4], b1v[4];
#pragma unroll
      for (int nn = 0; nn < 4; ++nn) {
        int rowb = cbase + nn * 32;
        b0v[nn] = *(const bf16x8*)&lB[s % 3][rowb * 64 + sl0];
        b1v[nn] = *(const bf16x8*)&lB[s % 3][rowb * 64 + sl1];
      }
      __builtin_amdgcn_s_setprio(1);
#pragma unroll
      for (int nn = 0; nn < 4; ++nn)
        acc1[nn] = __builtin_amdgcn_mfma_f32_16x16x32_bf16(a0, b0v[nn], acc1[nn], 0, 0, 0);
#pragma unroll
      for (int nn = 0; nn < 4; ++nn)
        acc1[nn] = __builtin_amdgcn_mfma_f32_16x16x32_bf16(a1, b1v[nn], acc1[nn], 0, 0, 0);
      __builtin_amdgcn_s_setprio(0);
      if (u == 3) {
        // relu + bias -> pch (local chunk cols 0..127)
#pragma unroll
        for (int nn = 0; nn < 4; ++nn) {
          int colc = cbase + nn * 32;
          float bs = b1[ny * 128 + colc];
#pragma unroll
          for (int q = 0; q < 4; ++q)
            pch[rowl + q][colc] = f2bf(fmaxf(acc1[nn][q] + bs, 0.f));
        }
        asm volatile("s_waitcnt lgkmcnt(0)" ::: "memory");
      }
      asm volatile("" ::: "memory");
      __builtin_amdgcn_s_barrier();
    }
    // lin2: 4 stages consume pch
#pragma unroll
    for (int v = 0; v < 4; ++v) {
      int s = 8 + ny * 8 + 4 + v;
      stage_top(s);
      int koff = (v >> 1) * 64;
      bf16x8 a0 = *(const bf16x8*)&pch[r0][koff + kqa];
      bf16x8 a1 = *(const bf16x8*)&pch[r0][koff + 32 + kqa];
      bf16x8 b0v[4], b1v[4];
#pragma unroll
      for (int nn = 0; nn < 4; ++nn) {
        int rowb = cbase + nn * 32;
        b0v[nn] = *(const bf16x8*)&lB[s % 3][rowb * 64 + sl0];
        b1v[nn] = *(const bf16x8*)&lB[s % 3][rowb * 64 + sl1];
      }
      __builtin_amdgcn_s_setprio(1);
#pragma unroll
      for (int nn = 0; nn < 4; ++nn)
        acc2[(v & 1) * 4 + nn] = __builtin_amdgcn_mfma_f32_16x16x32_bf16(a0, b0v[nn], acc2[(v & 1) * 4 + nn], 0, 0, 0);
#pragma unroll
      for (int nn = 0; nn < 4; ++nn)
        acc2[(v & 1) * 4 + nn] = __builtin_amdgcn_mfma_f32_16x16x32_bf16(a1, b1v[nn], acc2[(v & 1) * 4 + nn], 0, 0, 0);
      __builtin_amdgcn_s_setprio(0);
      asm volatile("" ::: "memory");
      __builtin_amdgcn_s_barrier();
    }
  }

  // ---- add(resid) + LN2 epilogue ----
  float x[8][4];
  float sums[4] = {0.f, 0.f, 0.f, 0.f}, sqs[4] = {0.f, 0.f, 0.f, 0.f};
#pragma unroll
  for (int m = 0; m < 8; ++m) {
    int col = ((m >> 2) << 7) + cbase + ((m & 3) << 5);
    float bs = b2[col];
#pragma unroll
    for (int q = 0; q < 4; ++q) {
      float v = acc2[m][q] + bs + resid[m][q];
      x[m][q] = v;
      sums[q] += v;
      sqs[q] += v * v;
    }
  }
#pragma unroll
  for (int q = 0; q < 4; ++q) {
    sums[q] += __shfl_xor(sums[q], 1); sqs[q] += __shfl_xor(sqs[q], 1);
    sums[q] += __shfl_xor(sums[q], 2); sqs[q] += __shfl_xor(sqs[q], 2);
    sums[q] += __shfl_xor(sums[q], 4); sqs[q] += __shfl_xor(sqs[q], 4);
    sums[q] += __shfl_xor(sums[q], 8); sqs[q] += __shfl_xor(sqs[q], 8);
  }
  __syncthreads();
  if ((lane & 15) == 0) {
#pragma unroll
    for (int q = 0; q < 4; ++q) {
      red[wn][rowl + q][0] = sums[q];
      red[wn][rowl + q][1] = sqs[q];
    }
  }
  __syncthreads();
#pragma unroll
  for (int q = 0; q < 4; ++q) {
    float ts = sums[q] + red[wn ^ 1][rowl + q][0];
    float tq = sqs[q] + red[wn ^ 1][rowl + q][1];
    float mu = ts * (1.f / 256.f);
    float var = tq * (1.f / 256.f) - mu * mu;
    float rs = rsqrtf(var + 1e-5f);
    int row = bm + rowl + q;
#pragma unroll
    for (int m = 0; m < 8; ++m) {
      int col = ((m >> 2) << 7) + cbase + ((m & 3) << 5);
      float o = (x[m][q] - mu) * rs * g2[col] + lb2[col];
      src[(size_t)row * 256 + col] = o;
      sbo[(size_t)row * 256 + col] = f2bf(o);
    }
  }
}

// ---------------- fused conv0: NCHW f32 hint -> NHWC32 bf16 (SiLU) ----------------
__global__ __launch_bounds__(256) void k_conv0(
    const float* __restrict__ x, const float* __restrict__ w,
    unsigned short* __restrict__ y)
{
  __shared__ float ws[16][28];
  int tid = threadIdx.x;
  for (int u = tid; u < 432; u += 256) {
    int co = u / 27, k = u - co * 27;
    int t = k / 3, ci = k - t * 3;
    ws[co][k] = w[((size_t)co * 3 + ci) * 9 + t];
  }
  __syncthreads();
  int h = blockIdx.x, b = blockIdx.y, wo = tid;
  float xin[3][3][3];
#pragma unroll
  for (int ci = 0; ci < 3; ++ci)
#pragma unroll
    for (int kh = 0; kh < 3; ++kh) {
      int hi = h + kh - 1;
#pragma unroll
      for (int kw = 0; kw < 3; ++kw) {
        int wi = wo + kw - 1;
        xin[ci][kh][kw] = ((unsigned)hi < 256u && (unsigned)wi < 256u)
            ? x[(((size_t)b * 3 + ci) << 16) + (hi << 8) + wi] : 0.f;
      }
    }
  float acc[16] = {};
#pragma unroll
  for (int t = 0; t < 9; ++t) {
    const int kh = t / 3, kw = t % 3;
#pragma unroll
    for (int ci = 0; ci < 3; ++ci) {
      float xv = xin[ci][kh][kw];
#pragma unroll
      for (int co = 0; co < 16; ++co)
        acc[co] = fmaf(xv, ws[co][t * 3 + ci], acc[co]);
    }
  }
  us8v o0, o1, zv;
#pragma unroll
  for (int q = 0; q < 8; ++q) {
    float v0 = acc[q];     v0 = v0 / (1.f + __expf(-v0)); o0[q] = f2bf(v0);
    float v1 = acc[q + 8]; v1 = v1 / (1.f + __expf(-v1)); o1[q] = f2bf(v1);
    zv[q] = 0;
  }
  unsigned short* yp = y + ((((size_t)b << 16) + (h << 8) + wo) << 5);
  *(us8v*)(yp) = o0; *(us8v*)(yp + 8) = o1;
  *(us8v*)(yp + 16) = zv; *(us8v*)(yp + 24) = zv;
}

// ---------------- halo-LDS direct conv (Ci=32 NHWC, Co<=32, 3x3, pad 1, SiLU) ----
template<int S>
__global__ __launch_bounds__(256) void k_conv_direct(
    const unsigned short* __restrict__ x, const unsigned short* __restrict__ wp,
    int ldw, unsigned short* __restrict__ y, int Hi, int Ho, int Wo, int lwt)
{
  constexpr int HR = 7 * S + 3;
  constexpr int HC = 15 * S + 3;
  constexpr int HP = HR * HC;
  __shared__ unsigned short xs[HP * 40];
  __shared__ unsigned short wsh[32 * 312];
  int tid = threadIdx.x, lane = tid & 63, wv = tid >> 6;
  int b = blockIdx.y;
  int tr = blockIdx.x >> lwt, tc = blockIdx.x & ((1 << lwt) - 1);
  int hi0 = tr * 8 * S - 1, wi0 = tc * 16 * S - 1;

  for (int u = tid; u < HP * 8; u += 256) {
    int pix = u >> 3, part = u & 7;
    int hr = pix / HC, hcc = pix - hr * HC;
    int hi = hi0 + hr, wi = wi0 + hcc;
    ushort4 v = {0, 0, 0, 0};
    if ((unsigned)hi < (unsigned)Hi && (unsigned)wi < (unsigned)Hi)
      v = *(const ushort4*)(x + ((size_t)(b * Hi + hi) * Hi + wi) * 32 + part * 4);
    *(ushort4*)(&xs[pix * 40 + part * 4]) = v;
  }
  for (int u = tid; u < 2304; u += 256) {
    int co = u / 72, kk = (u - co * 72) * 4;
    *(ushort4*)(&wsh[co * 312 + kk]) = *(const ushort4*)(wp + (size_t)co * ldw + kk);
  }
  __syncthreads();

  int cL = lane & 15, kq = (lane >> 4) << 3;
  f32x4 acc[2][2];
#pragma unroll
  for (int m = 0; m < 2; ++m)
#pragma unroll
    for (int n = 0; n < 2; ++n)
#pragma unroll
      for (int q = 0; q < 4; ++q) acc[m][n][q] = 0.f;

#pragma unroll
  for (int tap = 0; tap < 9; ++tap) {
    const int kh = tap / 3, kw = tap % 3;
    bf16x8 af[2], bfr[2];
#pragma unroll
    for (int m = 0; m < 2; ++m) {
      int hr = (wv * 2 + m) * S + kh;
      int hc = cL * S + kw;
      af[m] = *(const bf16x8*)&xs[(hr * HC + hc) * 40 + kq];
    }
#pragma unroll
    for (int n = 0; n < 2; ++n)
      bfr[n] = *(const bf16x8*)&wsh[(cL + n * 16) * 312 + tap * 32 + kq];
#pragma unroll
    for (int m = 0; m < 2; ++m)
#pragma unroll
      for (int n = 0; n < 2; ++n)
        acc[m][n] = __builtin_amdgcn_mfma_f32_16x16x32_bf16(af[m], bfr[n], acc[m][n], 0, 0, 0);
  }

  int wo0 = tc * 16 + ((lane >> 4) << 2);
#pragma unroll
  for (int m = 0; m < 2; ++m) {
    int ho = tr * 8 + wv * 2 + m;
#pragma unroll
    for (int n = 0; n < 2; ++n) {
      int co = cL + n * 16;
#pragma unroll
      for (int q = 0; q < 4; ++q) {
        float v = acc[m][n][q];
        v = v / (1.f + __expf(-v));
        y[((size_t)(b * Ho + ho) * Wo + wo0 + q) * 32 + co] = f2bf(v);
      }
    }
  }
}

// ---------------- conv weight permute, all convs 1-7 in one launch ----------------
struct WP8 { const float* w[8]; unsigned short* q[8]; };
__global__ __launch_bounds__(256) void k_wperm_all(WP8 p)
{
  const int CoPs[8]  = {128, 32, 32, 32, 128, 128, 256, 256};
  const int CiRs[8]  = {3, 16, 16, 32, 32, 96, 96, 256};
  const int CiPs[8]  = {3, 32, 32, 32, 32, 96, 96, 256};
  const int Kpads[8] = {64, 288, 288, 288, 320, 896, 896, 2304};
  const int Cos[8]   = {16, 16, 32, 32, 96, 96, 256, 256};
  int i = blockIdx.y + 1;
  const float* w = p.w[i];
  unsigned short* wp = p.q[i];
  int Kpad = Kpads[i], CiP = CiPs[i], CiR = CiRs[i], Co = Cos[i];
  int total = CoPs[i] * Kpad;
  for (int idx = blockIdx.x * 256 + threadIdx.x; idx < total; idx += gridDim.x * 256) {
    int co = idx / Kpad, k = idx - co * Kpad;
    int t = k / CiP, ci = k - t * CiP;
    float v = 0.f;
    if (co < Co && t < 9 && ci < CiR) v = w[((size_t)co * CiR + ci) * 9 + t];
    wp[idx] = f2bf(v);
  }
}

// ---------------- merged prep: weight cvt/pad + pos table, 6 segments ----------
struct PrepArgs {
  const float *ipw, *outw, *l1w, *l2w, *l1b;
  unsigned short *wqkvb, *outwb, *l1wb, *l2wb, *posb;
  float *l1bp;
};
__global__ __launch_bounds__(256) void k_prep(PrepArgs a)
{
  int seg = blockIdx.y;
  int idx0 = blockIdx.x * 256 + threadIdx.x;
  int stride = gridDim.x * 256;
  if (seg == 0) {
    for (int i = idx0; i < 8 * 768 * 256; i += stride) a.wqkvb[i] = f2bf(a.ipw[i]);
  } else if (seg == 1) {
    for (int i = idx0; i < 8 * 256 * 256; i += stride) a.outwb[i] = f2bf(a.outw[i]);
  } else if (seg == 2) {
    for (int i = idx0; i < 8 * 1152 * 256; i += stride) {
      int l = i / (1152 * 256), r = (i >> 8) % 1152, c = i & 255;
      float v = (r < 1025) ? a.l1w[((size_t)l * 1025 + r) * 256 + c] : 0.f;
      a.l1wb[i] = f2bf(v);
    }
  } else if (seg == 3) {
    for (int i = idx0; i < 8 * 256 * 1152; i += stride) {
      int l = i / (256 * 1152), rc = i % (256 * 1152), r = rc / 1152, c = rc - (rc / 1152) * 1152;
      float v = (c < 1025) ? a.l2w[((size_t)l * 256 + r) * 1025 + c] : 0.f;
      a.l2wb[i] = f2bf(v);
    }
  } else if (seg == 4) {
    for (int i = idx0; i < 8 * 1152; i += stride) {
      int l = i / 1152, c = i - l * 1152;
      a.l1bp[i] = (c < 1025) ? a.l1b[l * 1025 + c] : 0.f;
    }
  } else {
    for (int i = idx0; i < 1024 * 256; i += stride) {
      int n = i >> 8, c = i & 255;
      int ih = n >> 5, iw = n & 31;
      float coord = (c < 128) ? (float)(ih + 1) : (float)(iw + 1);
      int cc = c & 127;
      float e = (float)((cc >> 1) << 1) * (1.f / 128.f);
      float t = coord / powf(10000.f, e);
      a.posb[i] = f2bf((cc & 1) ? cosf(t) : sinf(t));
    }
  }
}

// ---------------- neighborhood attention (7x7), query-tiled, bf16 K/V in LDS ----
__global__ __launch_bounds__(256) void k_attn(
    const unsigned short* __restrict__ qkv, unsigned short* __restrict__ ctx)
{
  __shared__ unsigned short k_ldsu[848 * 8];
  __shared__ unsigned short v_lds[848 * 8];
  __shared__ float p_lds[64 * 50];
  int bx = blockIdx.x;
  int b = bx >> 4, tile = bx & 15;
  int th8 = ((tile >> 2) << 3), tw8 = ((tile & 3) << 3);
  int g = blockIdx.y;
  int tid = threadIdx.x, lane = tid & 63, wid = tid >> 6;
  int h0e = max(th8 - 3, 0), h1e = min(th8 + 10, 31);
  int w0e = max(tw8 - 3, 0), w1e = min(tw8 + 10, 31);
  int nh = h1e - h0e + 1, nw = w1e - w0e + 1;
  int nkeys = nh * nw, nslots = nkeys * 4;
  unsigned int magic = (65536u + (unsigned)nw - 1u) / (unsigned)nw;
  size_t qbase = (size_t)((unsigned)b << 10) * 768;

#pragma unroll
  for (int i = 0; i < 4; ++i) {
    int base = i * 256 + wid * 64;
    if (base < 784) {
      int s = min(base + lane, nslots - 1);
      int uidx = s >> 2, chunk = s & 3;
      int hh = (int)(((unsigned)uidx * magic) >> 16);
      int ww = uidx - hh * nw;
      hh += h0e; ww += w0e;
      const unsigned short* rp = qkv + qbase + (size_t)((hh << 5) + ww) * 768 + (g << 5) + chunk * 8;
      GLD16(rp + 256, &k_ldsu[base * 8]);
      GLD16(rp + 512, &v_lds[base * 8]);
    }
  }
  __syncthreads();

  int q = tid >> 2, dq = tid & 3;
  int qh = th8 + (q >> 3), qw = tw8 + (q & 7);
  const float scale = 0.17677669529663687f;
  const unsigned short* qp = qkv + qbase + (size_t)((qh << 5) + qw) * 768 + (g << 5) + dq * 8;
  us8v uq = *(const us8v*)qp;
  float qr[8];
#pragma unroll
  for (int t = 0; t < 8; ++t) qr[t] = bf2f(uq[t]) * scale;

  int rbase[7], cofs[7];
  bool rval[7], cval[7];
#pragma unroll
  for (int d = 0; d < 7; ++d) {
    int mh = qh - 3 + d;
    rval[d] = (unsigned)mh < 32u;
    rbase[d] = (mh - h0e) * nw;
    int mw = qw - 3 + d;
    cval[d] = (unsigned)mw < 32u;
    cofs[d] = mw - w0e;
  }

  float m = -1e30f;
#pragma unroll
  for (int kk = 0; kk < 49; ++kk) {
    const int d7 = kk / 7, r7 = kk % 7;
    bool valid = rval[d7] && cval[r7];
    int uidx = valid ? (rbase[d7] + cofs[r7]) : 0;
    us8v uk = *(const us8v*)&k_ldsu[uidx * 32 + dq * 8];
    float d = 0.f;
#pragma unroll
    for (int t = 0; t < 8; ++t) d = fmaf(qr[t], bf2f(uk[t]), d);
    d += __shfl_xor(d, 1);
    d += __shfl_xor(d, 2);
    float s_kk = valid ? d : -1e30f;
    m = fmaxf(m, s_kk);
    if (dq == (kk & 3)) p_lds[q * 50 + kk] = s_kk;
  }
  float sum = 0.f;
  for (int kk = dq; kk < 49; kk += 4) {
    float e = __expf(p_lds[q * 50 + kk] - m);
    p_lds[q * 50 + kk] = e;
    sum += e;
  }
  sum += __shfl_xor(sum, 1);
  sum += __shfl_xor(sum, 2);
  float inv = 1.f / sum;

  float acc[8] = {};
#pragma unroll
  for (int kk = 0; kk < 49; ++kk) {
    const int d7 = kk / 7, r7 = kk % 7;
    int uidx = (rval[d7] && cval[r7]) ? (rbase[d7] + cofs[r7]) : 0;
    float pb = p_lds[q * 50 + kk];
    us8v uv = *(const us8v*)&v_lds[uidx * 32 + dq * 8];
#pragma unroll
    for (int t = 0; t < 8; ++t) acc[t] = fmaf(pb, bf2f(uv[t]), acc[t]);
  }
  unsigned short* op = ctx + ((size_t)((b << 10) + (qh << 5) + qw) << 8) + (g << 5) + dq * 8;
  us8v out;
#pragma unroll
  for (int t = 0; t < 8; ++t) out[t] = f2bf(acc[t] * inv);
  *(us8v*)op = out;
}

// ---------------- (B,1024,256) f32 -> (B,256,32,32) ----------------
__global__ void k_nxc_to_cxn(const float* __restrict__ x, float* __restrict__ y)
{
  __shared__ float t[32][33];
  int b = blockIdx.z;
  int c0 = blockIdx.x * 32, n0 = blockIdx.y * 32;
  int tx = threadIdx.x, ty = threadIdx.y;
  t[ty][tx] = x[((size_t)(b * 1024 + n0 + ty)) * 256 + c0 + tx];
  __syncthreads();
  y[((size_t)(b * 256 + c0 + ty)) * 1024 + n0 + tx] = t[tx][ty];
}

extern "C" void kernel_launch(void* const* d_in, const int* in_sizes, int n_in,
                              void* d_out, int out_size, void* d_ws, size_t ws_size,
                              hipStream_t stream)
{
  const float* hint = (const float*)d_in[0];
  const float* cw[8];
  for (int i = 0; i < 8; ++i) cw[i] = (const float*)d_in[1 + i];
  const float* ipw  = (const float*)d_in[9];
  const float* ipb  = (const float*)d_in[10];
  const float* outw = (const float*)d_in[11];
  const float* outb = (const float*)d_in[12];
  const float* l1w  = (const float*)d_in[13];
  const float* l1b  = (const float*)d_in[14];
  const float* l2w  = (const float*)d_in[15];
  const float* l2b  = (const float*)d_in[16];
  const float* g1   = (const float*)d_in[17];
  const float* b1   = (const float*)d_in[18];
  const float* g2   = (const float*)d_in[19];
  const float* b2   = (const float*)d_in[20];

  float* ws = (float*)d_ws;
  size_t off = 0;
  float* bufA = ws + off; off += 8388608;
  float* bufB = ws + off; off += 8388608;
  float* src  = ws + off; off += 2097152;
  unsigned short* srcb = (unsigned short*)(ws + off); off += 1048576;
  unsigned short* posb = (unsigned short*)(ws + off); off += 131072;
  float* posqk = ws + off; off += 4194304;
  unsigned short* wqkvb = (unsigned short*)(ws + off); off += 786432;
  unsigned short* outwb = (unsigned short*)(ws + off); off += 262144;
  unsigned short* l1wb  = (unsigned short*)(ws + off); off += 1179648;
  unsigned short* l2wb  = (unsigned short*)(ws + off); off += 1179648;
  float* l1bp = ws + off; off += 9216;
  unsigned short* cwp[8];
  const int CoPs[8]  = {128, 32, 32, 32, 128, 128, 256, 256};
  const int Kpads[8] = {64, 288, 288, 288, 320, 896, 896, 2304};
  for (int i = 0; i < 8; ++i) { cwp[i] = (unsigned short*)(ws + off); off += ((size_t)CoPs[i] * Kpads[i] + 1) / 2; }
  unsigned short* zpage = (unsigned short*)(ws + off); off += 64;

  hipMemsetAsync(zpage, 0, 256, stream);

  // ---- prep ----
  PrepArgs pa;
  pa.ipw = ipw; pa.outw = outw; pa.l1w = l1w; pa.l2w = l2w; pa.l1b = l1b;
  pa.wqkvb = wqkvb; pa.outwb = outwb; pa.l1wb = l1wb; pa.l2wb = l2wb;
  pa.posb = posb; pa.l1bp = l1bp;
  k_prep<<<dim3(256, 6), 256, 0, stream>>>(pa);
  WP8 wpargs;
  for (int i = 0; i < 8; ++i) { wpargs.w[i] = cw[i]; wpargs.q[i] = cwp[i]; }
  k_wperm_all<<<dim3(64, 7), 256, 0, stream>>>(wpargs);

  unsigned short* bufAu = (unsigned short*)bufA;
  unsigned short* bufBu = (unsigned short*)bufB;

#define GEMM_TAIL nullptr, 0, 0, 0, 0, 0, 0, nullptr, nullptr
  // ---- conv stack ----
  k_conv0<<<dim3(256, 8), 256, 0, stream>>>(hint, cw[0], bufAu);
  k_conv_direct<1><<<dim3(512, 8), 256, 0, stream>>>(bufAu, cwp[1], 288, bufBu, 256, 256, 256, 4);
  k_conv_direct<2><<<dim3(128, 8), 256, 0, stream>>>(bufBu, cwp[2], 288, bufAu, 256, 128, 128, 3);
  k_conv_direct<1><<<dim3(128, 8), 256, 0, stream>>>(bufAu, cwp[3], 288, bufBu, 128, 128, 128, 3);
  k_gemm<128, 128, 512, 1, 0, 5><<<dim3(256, 1), 512, 0, stream>>>(   // conv4
      bufBu, 0, cwp[4], 320, nullptr, nullptr, nullptr, bufAu, 96, 320, 96, 2, 1,
      0, 0, zpage, 32, 128, 2, 6, 1, 0, nullptr, nullptr);
  k_gemm<128, 128, 512, 1, 0, 14><<<dim3(256, 1), 512, 0, stream>>>(  // conv5
      bufAu, 0, cwp[5], 896, nullptr, nullptr, nullptr, bufBu, 96, 896, 96, 2, 1,
      0, 0, zpage, 96, 64, 1, 6, 171, 9, nullptr, nullptr);
  k_gemm<64, 128, 512, 1, 0, 14><<<dim3(128, 2), 512, 0, stream>>>(   // conv6
      bufBu, 0, cwp[6], 896, nullptr, nullptr, nullptr, bufAu, 256, 896, 256, 2, 1,
      0, 0, zpage, 96, 64, 2, 5, 171, 9, nullptr, nullptr);
  k_gemm<64, 128, 512, 1><<<dim3(128, 2), 512, 0, stream>>>(          // conv7
      bufAu, 0, cwp[7], 2304, nullptr, nullptr, src, srcb, 256, 2304, 256, 0, 2,
      0, 0, zpage, 256, 32, 1, 5, 1, 3, nullptr, nullptr);

  // ---- posqk[l] = pos @ [Wq;Wk]^T, batched over 8 layers ----
  k_gemm<64, 128, 512, 0, 0, 4><<<dim3(16, 4, 8), 512, 0, stream>>>(
      posb, 256, wqkvb, 256, nullptr, nullptr, posqk, nullptr, 512, 256, 512, 0, 0,
      196608LL, 524288LL, GEMM_TAIL);

  unsigned short* qkvb = bufAu;
  unsigned short* ctx  = (unsigned short*)(bufA + 3145728);

  // ---- transformer layers ----
  for (int l = 0; l < 8; ++l) {
    const unsigned short* wqkv_l = wqkvb + (size_t)l * 768 * 256;
    const float* ipb_l  = ipb  + (size_t)l * 768;
    const unsigned short* outw_l = outwb + (size_t)l * 256 * 256;
    const float* outb_l = outb + (size_t)l * 256;
    const unsigned short* l1w_l = l1wb + (size_t)l * 1152 * 256;
    const float* l1b_l  = l1bp + (size_t)l * 1152;
    const unsigned short* l2w_l = l2wb + (size_t)l * 256 * 1152;
    const float* l2b_l  = l2b  + (size_t)l * 256;
    const float* posqk_l = posqk + (size_t)l * 524288;
    const float* g1_l = g1 + l * 256; const float* b1_l = b1 + l * 256;
    const float* g2_l = g2 + l * 256; const float* b2_l = b2 + l * 256;

    k_gemm<64, 128, 512, 0, 0, 4><<<dim3(128, 6), 512, 0, stream>>>(   // QKV
        srcb, 256, wqkv_l, 256, ipb_l, posqk_l, nullptr, qkvb, 768, 256, 768, 0, 1,
        0, 0, GEMM_TAIL);
    k_attn<<<dim3(128, 8), 256, 0, stream>>>(qkvb, ctx);
    k_mlp<<<dim3(256), 256, 0, stream>>>(                              // tail fused
        ctx, outw_l, outb_l, l1w_l, l1b_l, l2w_l, l2b_l,
        src, srcb, g1_l, b1_l, g2_l, b2_l);
  }

  // ---- output ----
  k_nxc_to_cxn<<<dim3(8, 32, 8), dim3(32, 32), 0, stream>>>(src, (float*)d_out);
}

// Round 19
// 838.162 us; speedup vs baseline: 1.1806x; 1.1806x over previous
//
#include <hip/hip_runtime.h>
#include <hip/hip_bf16.h>

// B=8, C=256, NH=8, DH=32, N=1024 (32x32), L=8, DFF=1025 (pad 1152)
// conv0: fused direct. convs 1-3: halo-LDS direct MFMA. convs 4-7: implicit-GEMM.
// GEMM: BK=64, 3-bit XOR LDS swizzle, counted-vmcnt double-buffer pipeline.
// k_mlp: 80 uniform 16KB weight stages, ring-4 LDS, depth-3 prefetch (r17).
// k_attn additionally warms the next k_mlp's weights into every XCD L2.

typedef __bf16 bf16x8 __attribute__((ext_vector_type(8)));
typedef float f32x4 __attribute__((ext_vector_type(4)));
typedef unsigned short us8v __attribute__((ext_vector_type(8)));

__device__ __forceinline__ unsigned short f2bf(float f) {
  unsigned int u = __float_as_uint(f);
  unsigned int r = (u + 0x7fffu + ((u >> 16) & 1u)) >> 16;
  return (unsigned short)r;
}
__device__ __forceinline__ float bf2f(unsigned short h) {
  return __uint_as_float(((unsigned int)h) << 16);
}

#define GLD16(src, dst)                                                        \
  __builtin_amdgcn_global_load_lds(                                            \
      (const __attribute__((address_space(1))) unsigned int*)(src),            \
      (__attribute__((address_space(3))) unsigned int*)(dst), 16, 0, 0)

// ---------------- unified bf16 MFMA GEMM, BK=64, counted-vmcnt pipeline --------
template<int BM, int BN, int NT, int MODE, int LNF = 0, int KTC = 0>
__global__ __launch_bounds__(NT) void k_gemm(
    const unsigned short* __restrict__ A, int lda,
    const unsigned short* __restrict__ Bw, int ldb,
    const float* __restrict__ bias, const float* __restrict__ posadd,
    float* __restrict__ C, unsigned short* __restrict__ Cb, int ldc,
    int K, int Nstore, int act, int omode, long long zsB, long long zsC,
    const unsigned short* __restrict__ zpage, int Ci, int Hi, int stride, int lw,
    int divm, int divs, const float* __restrict__ lng, const float* __restrict__ lnb)
{
  constexpr int NW = NT / 64;
  constexpr int NWN = (NT == 512) ? 4 : ((BN >= 128) ? 2 : 1);
  constexpr int NWM = NW / NWN;
  constexpr int WM = BM / NWM, WN = BN / NWN;
  constexpr int MF = WM / 16, NF = WN / 16;
  constexpr int AIS = (BM * 8) / NT;
  constexpr int BIS = (BN * 8) / NT;
  __shared__ unsigned short lA[2][BM * 64];
  __shared__ unsigned short lB[2][BN * 64];
  int tid = threadIdx.x, lane = tid & 63, wid = tid >> 6;
  int bm = blockIdx.x * BM, bn = blockIdx.y * BN;
  const unsigned short* Bz = Bw + (size_t)blockIdx.z * zsB;

  int j = (lane & 7) ^ (lane >> 3);   // source chunk this lane fetches
  int e8 = (j & 3) << 3;
  int halfl = j >> 2;

  size_t arow[AIS], brow[BIS];
  int hb[AIS], wb[AIS];
  size_t ab[AIS];
#pragma unroll
  for (int i = 0; i < AIS; ++i) {
    int rr = (wid + i * NW) * 8 + (lane >> 3);
    if constexpr (MODE == 0) {
      arow[i] = (size_t)(bm + rr) * lda + (j << 3);
    } else {
      int pos = bm + rr;
      int b = pos >> (2 * lw);
      int rem = pos & ((1 << (2 * lw)) - 1);
      int ho = rem >> lw, wo = rem & ((1 << lw) - 1);
      hb[i] = ho * stride - 1;
      wb[i] = wo * stride - 1;
      ab[i] = (size_t)b * Hi * Hi * Ci;
    }
  }
#pragma unroll
  for (int i = 0; i < BIS; ++i)
    brow[i] = (size_t)(bn + (wid + i * NW) * 8 + (lane >> 3)) * ldb + (j << 3);

  auto stage = [&](int buf, int kt) {
    if constexpr (MODE == 1) {
      int s0 = kt * 2, s1 = s0 + 1;
      int t0 = (s0 * divm) >> divs, t1 = (s1 * divm) >> divs;
      int cipw = Ci >> 5;
      int cc0 = (s0 - t0 * cipw) << 5, cc1 = (s1 - t1 * cipw) << 5;
      int kh0 = (t0 * 171) >> 9, kw0 = t0 - kh0 * 3;
      int kh1 = (t1 * 171) >> 9, kw1 = t1 - kh1 * 3;
      int kh = halfl ? kh1 : kh0;
      int kw = halfl ? kw1 : kw0;
      int cco = halfl ? cc1 : cc0;
      bool tv = (halfl ? t1 : t0) < 9;
#pragma unroll
      for (int i = 0; i < AIS; ++i) {
        int hi = hb[i] + kh, wi = wb[i] + kw;
        const unsigned short* ap =
            (tv && (unsigned)hi < (unsigned)Hi && (unsigned)wi < (unsigned)Hi)
                ? (A + ab[i] + (size_t)(hi * Hi + wi) * Ci + cco + e8)
                : zpage;
        GLD16(ap, &lA[buf][(wid + i * NW) * 512]);
      }
    } else {
#pragma unroll
      for (int i = 0; i < AIS; ++i)
        GLD16(A + arow[i] + kt * 64, &lA[buf][(wid + i * NW) * 512]);
    }
#pragma unroll
    for (int i = 0; i < BIS; ++i)
      GLD16(Bz + brow[i] + kt * 64, &lB[buf][(wid + i * NW) * 512]);
  };

  f32x4 acc[MF][NF];
#pragma unroll
  for (int m = 0; m < MF; ++m)
#pragma unroll
    for (int n = 0; n < NF; ++n)
#pragma unroll
      for (int q = 0; q < 4; ++q) acc[m][n][q] = 0.f;

  int wn = wid % NWN, wm = wid / NWN;
  int r0 = wm * WM + (lane & 15);
  int c0 = wn * WN + (lane & 15);
  int sl0 = (((lane >> 4)) ^ (lane & 7)) << 3;
  int sl1 = (((lane >> 4) + 4) ^ (lane & 7)) << 3;
  const int nkt = (KTC > 0) ? KTC : (K >> 6);
  int cur = 0;
  stage(0, 0);
#pragma unroll
  for (int kt = 0; kt < nkt; ++kt) {
    if (kt + 1 < nkt) {
      stage(cur ^ 1, kt + 1);
      asm volatile("s_waitcnt vmcnt(%0)" : : "n"(AIS + BIS) : "memory");
    } else {
      asm volatile("s_waitcnt vmcnt(0)" : : : "memory");
    }
    __builtin_amdgcn_s_barrier();
    asm volatile("" ::: "memory");
    bf16x8 a0[MF], a1[MF], b0[NF], b1[NF];
#pragma unroll
    for (int m = 0; m < MF; ++m) {
      a0[m] = *(const bf16x8*)&lA[cur][(r0 + m * 16) * 64 + sl0];
      a1[m] = *(const bf16x8*)&lA[cur][(r0 + m * 16) * 64 + sl1];
    }
#pragma unroll
    for (int n = 0; n < NF; ++n) {
      b0[n] = *(const bf16x8*)&lB[cur][(c0 + n * 16) * 64 + sl0];
      b1[n] = *(const bf16x8*)&lB[cur][(c0 + n * 16) * 64 + sl1];
    }
#pragma unroll
    for (int m = 0; m < MF; ++m)
#pragma unroll
      for (int n = 0; n < NF; ++n)
        acc[m][n] = __builtin_amdgcn_mfma_f32_16x16x32_bf16(a0[m], b0[n], acc[m][n], 0, 0, 0);
#pragma unroll
    for (int m = 0; m < MF; ++m)
#pragma unroll
      for (int n = 0; n < NF; ++n)
        acc[m][n] = __builtin_amdgcn_mfma_f32_16x16x32_bf16(a1[m], b1[n], acc[m][n], 0, 0, 0);
    asm volatile("" ::: "memory");
    __builtin_amdgcn_s_barrier();
    cur ^= 1;
  }

  int colb = bn + wn * WN + (lane & 15);
  int rowb = bm + wm * WM + ((lane >> 4) << 2);
  float* Cz = C ? C + (size_t)blockIdx.z * zsC : nullptr;
  unsigned short* Cbz = Cb ? Cb + (size_t)blockIdx.z * zsC : nullptr;
#pragma unroll
  for (int n = 0; n < NF; ++n) {
    int col = colb + n * 16;
    if (col >= Nstore) continue;
    float bs = bias ? bias[col] : 0.f;
#pragma unroll
    for (int m = 0; m < MF; ++m) {
#pragma unroll
      for (int q = 0; q < 4; ++q) {
        int row = rowb + m * 16 + q;
        float v = acc[m][n][q] + bs;
        if (posadd && col < 512) v += posadd[((row & 1023) << 9) + col];
        if (act == 1) v = fmaxf(v, 0.f);
        else if (act == 2) v = v / (1.f + __expf(-v));
        size_t off = (size_t)row * ldc + col;
        if (omode == 0) Cz[off] = v;
        else if (omode == 1) Cbz[off] = f2bf(v);
        else { Cz[off] = v; Cbz[off] = f2bf(v); }
      }
    }
  }
}

// ---------------- fused layer tail: 80-stage depth-3 weight pipeline (r17) ------
__global__ __launch_bounds__(256) void k_mlp(
    const unsigned short* __restrict__ ctx, const unsigned short* __restrict__ wo,
    const float* __restrict__ ob,
    const unsigned short* __restrict__ w1, const float* __restrict__ b1,
    const unsigned short* __restrict__ w2, const float* __restrict__ b2,
    float* __restrict__ src, unsigned short* __restrict__ sbo,
    const float* __restrict__ g1, const float* __restrict__ lb1,
    const float* __restrict__ g2, const float* __restrict__ lb2)
{
  __shared__ unsigned short aT[4][32 * 64];      // 16 KB
  __shared__ unsigned short lB[4][128 * 64];     // 64 KB ring (4 x 16KB)
  __shared__ unsigned short ffl[32][1160];       // 74.25 KB
  __shared__ float red[2][32][2];
  int tid = threadIdx.x, lane = tid & 63, wid = tid >> 6;
  int bm = blockIdx.x << 5;
  int rsrc = lane >> 3;
  int jj8 = ((lane & 7) ^ rsrc) << 3;

  // stage A (ctx): 4 k-tiles (issued first -> oldest)
  {
    int rr = wid * 8 + rsrc;
    const unsigned short* ap = ctx + (size_t)(bm + rr) * 256 + jj8;
#pragma unroll
    for (int kt = 0; kt < 4; ++kt)
      GLD16(ap + kt * 64, &aT[kt][wid * 512]);
  }

  // linear weight-stage issue, s in [0,80)
  auto issue = [&](int s) {
    const unsigned short* base;
    int ld, coloff, row0;
    if (s < 8)       { base = wo; ld = 256;  coloff = (s >> 1) * 64; row0 = (s & 1) * 128; }
    else if (s < 44) { int t = s - 8;  base = w1; ld = 256;  coloff = (t & 3) * 64; row0 = (t >> 2) * 128; }
    else             { int t = s - 44; base = w2; ld = 1152; coloff = (t >> 1) * 64; row0 = (t & 1) * 128; }
    int buf = s & 3;
#pragma unroll
    for (int i = 0; i < 4; ++i) {
      int rr = row0 + (wid + i * 4) * 8 + rsrc;
      GLD16(base + (size_t)rr * ld + coloff + jj8, &lB[buf][(wid + i * 4) * 512]);
    }
  };
  issue(0); issue(1); issue(2); issue(3);

  int wn = wid & 1, wm = wid >> 1;
  int r0 = wm * 16 + (lane & 15);
  int sl0 = ((lane >> 4) ^ (lane & 7)) << 3;
  int sl1 = (((lane >> 4) + 4) ^ (lane & 7)) << 3;
  int kqa = (lane >> 4) << 3;
  int cbase = wn * 16 + (lane & 15);              // frag col base within 128-half
  int rowl = wm * 16 + ((lane >> 4) << 2);

  // ---- phase A: out-proj, stages 0..7 ----
  f32x4 acco[8];
#pragma unroll
  for (int m = 0; m < 8; ++m)
#pragma unroll
    for (int q = 0; q < 4; ++q) acco[m][q] = 0.f;
#pragma unroll
  for (int s = 0; s < 8; ++s) {
    const int kt = s >> 1, rh = s & 1;
    asm volatile("s_waitcnt vmcnt(12)" ::: "memory");
    __builtin_amdgcn_s_barrier();
    asm volatile("" ::: "memory");
    bf16x8 a0 = *(const bf16x8*)&aT[kt][r0 * 64 + sl0];
    bf16x8 a1 = *(const bf16x8*)&aT[kt][r0 * 64 + sl1];
    bf16x8 b0v[4], b1v[4];
#pragma unroll
    for (int nn = 0; nn < 4; ++nn) {
      int rowb = cbase + nn * 32;
      b0v[nn] = *(const bf16x8*)&lB[s & 3][rowb * 64 + sl0];
      b1v[nn] = *(const bf16x8*)&lB[s & 3][rowb * 64 + sl1];
    }
    __builtin_amdgcn_s_setprio(1);
#pragma unroll
    for (int nn = 0; nn < 4; ++nn)
      acco[rh * 4 + nn] = __builtin_amdgcn_mfma_f32_16x16x32_bf16(a0, b0v[nn], acco[rh * 4 + nn], 0, 0, 0);
#pragma unroll
    for (int nn = 0; nn < 4; ++nn)
      acco[rh * 4 + nn] = __builtin_amdgcn_mfma_f32_16x16x32_bf16(a1, b1v[nn], acco[rh * 4 + nn], 0, 0, 0);
    __builtin_amdgcn_s_setprio(0);
    asm volatile("" ::: "memory");
    __builtin_amdgcn_s_barrier();
    issue(s + 4);
  }

  // ---- add + LN1 -> resid regs + aT (swizzled bf16) ----
  float resid[8][4];
  {
    float x[8][4];
    float sums[4] = {0.f, 0.f, 0.f, 0.f}, sqs[4] = {0.f, 0.f, 0.f, 0.f};
#pragma unroll
    for (int m = 0; m < 8; ++m) {
      int col = ((m >> 2) << 7) + cbase + ((m & 3) << 5);
      float bs = ob[col];
#pragma unroll
      for (int q = 0; q < 4; ++q) {
        float v = acco[m][q] + bs + src[(size_t)(bm + rowl + q) * 256 + col];
        x[m][q] = v;
        sums[q] += v;
        sqs[q] += v * v;
      }
    }
#pragma unroll
    for (int q = 0; q < 4; ++q) {
      sums[q] += __shfl_xor(sums[q], 1); sqs[q] += __shfl_xor(sqs[q], 1);
      sums[q] += __shfl_xor(sums[q], 2); sqs[q] += __shfl_xor(sqs[q], 2);
      sums[q] += __shfl_xor(sums[q], 4); sqs[q] += __shfl_xor(sqs[q], 4);
      sums[q] += __shfl_xor(sums[q], 8); sqs[q] += __shfl_xor(sqs[q], 8);
    }
    if ((lane & 15) == 0) {
#pragma unroll
      for (int q = 0; q < 4; ++q) {
        red[wn][rowl + q][0] = sums[q];
        red[wn][rowl + q][1] = sqs[q];
      }
    }
    asm volatile("s_waitcnt lgkmcnt(0)" ::: "memory");
    __builtin_amdgcn_s_barrier();
    asm volatile("" ::: "memory");
#pragma unroll
    for (int q = 0; q < 4; ++q) {
      float ts = sums[q] + red[wn ^ 1][rowl + q][0];
      float tq = sqs[q] + red[wn ^ 1][rowl + q][1];
      float mu = ts * (1.f / 256.f);
      float var = tq * (1.f / 256.f) - mu * mu;
      float rs = rsqrtf(var + 1e-5f);
      int r = rowl + q;
#pragma unroll
      for (int m = 0; m < 8; ++m) {
        int col = ((m >> 2) << 7) + cbase + ((m & 3) << 5);
        float o = (x[m][q] - mu) * rs * g1[col] + lb1[col];
        resid[m][q] = o;
        int kt = col >> 6, jjc = (col >> 3) & 7, e = col & 7;
        aT[kt][r * 64 + ((jjc ^ (r & 7)) << 3) + e] = f2bf(o);
      }
    }
  }
  asm volatile("s_waitcnt lgkmcnt(0)" ::: "memory");
  __builtin_amdgcn_s_barrier();
  asm volatile("" ::: "memory");

  // ---- phase B: lin1 + relu -> ffl, stages 8..43 ----
  for (int ny = 0; ny < 9; ++ny) {
    f32x4 acc1[4];
#pragma unroll
    for (int nn = 0; nn < 4; ++nn)
#pragma unroll
      for (int q = 0; q < 4; ++q) acc1[nn][q] = 0.f;
#pragma unroll
    for (int kt = 0; kt < 4; ++kt) {
      int s = 8 + ny * 4 + kt;
      asm volatile("s_waitcnt vmcnt(12)" ::: "memory");
      __builtin_amdgcn_s_barrier();
      asm volatile("" ::: "memory");
      bf16x8 a0 = *(const bf16x8*)&aT[kt][r0 * 64 + sl0];
      bf16x8 a1 = *(const bf16x8*)&aT[kt][r0 * 64 + sl1];
      bf16x8 b0v[4], b1v[4];
#pragma unroll
      for (int nn = 0; nn < 4; ++nn) {
        int rowb = cbase + nn * 32;
        b0v[nn] = *(const bf16x8*)&lB[s & 3][rowb * 64 + sl0];
        b1v[nn] = *(const bf16x8*)&lB[s & 3][rowb * 64 + sl1];
      }
      __builtin_amdgcn_s_setprio(1);
#pragma unroll
      for (int nn = 0; nn < 4; ++nn)
        acc1[nn] = __builtin_amdgcn_mfma_f32_16x16x32_bf16(a0, b0v[nn], acc1[nn], 0, 0, 0);
#pragma unroll
      for (int nn = 0; nn < 4; ++nn)
        acc1[nn] = __builtin_amdgcn_mfma_f32_16x16x32_bf16(a1, b1v[nn], acc1[nn], 0, 0, 0);
      __builtin_amdgcn_s_setprio(0);
      asm volatile("" ::: "memory");
      __builtin_amdgcn_s_barrier();
      issue(s + 4);
    }
#pragma unroll
    for (int nn = 0; nn < 4; ++nn) {
      int col = ny * 128 + cbase + nn * 32;
      float bs = b1[col];
#pragma unroll
      for (int q = 0; q < 4; ++q)
        ffl[rowl + q][col] = f2bf(fmaxf(acc1[nn][q] + bs, 0.f));
    }
  }
  asm volatile("s_waitcnt lgkmcnt(0)" ::: "memory");

  // ---- phase C: lin2, stages 44..79 ----
  f32x4 acc[8];
#pragma unroll
  for (int m = 0; m < 8; ++m)
#pragma unroll
    for (int q = 0; q < 4; ++q) acc[m][q] = 0.f;
  for (int kt = 0; kt < 18; ++kt) {
#pragma unroll
    for (int rh = 0; rh < 2; ++rh) {
      int t = kt * 2 + rh;
      if (t <= 32) { asm volatile("s_waitcnt vmcnt(12)" ::: "memory"); }
      else if (t == 33) { asm volatile("s_waitcnt vmcnt(8)" ::: "memory"); }
      else if (t == 34) { asm volatile("s_waitcnt vmcnt(4)" ::: "memory"); }
      else { asm volatile("s_waitcnt vmcnt(0)" ::: "memory"); }
      __builtin_amdgcn_s_barrier();
      asm volatile("" ::: "memory");
      bf16x8 a0 = *(const bf16x8*)&ffl[r0][kt * 64 + kqa];
      bf16x8 a1 = *(const bf16x8*)&ffl[r0][kt * 64 + 32 + kqa];
      bf16x8 b0v[4], b1v[4];
#pragma unroll
      for (int nn = 0; nn < 4; ++nn) {
        int rowb = cbase + nn * 32;
        b0v[nn] = *(const bf16x8*)&lB[(44 + t) & 3][rowb * 64 + sl0];
        b1v[nn] = *(const bf16x8*)&lB[(44 + t) & 3][rowb * 64 + sl1];
      }
      __builtin_amdgcn_s_setprio(1);
#pragma unroll
      for (int nn = 0; nn < 4; ++nn)
        acc[rh * 4 + nn] = __builtin_amdgcn_mfma_f32_16x16x32_bf16(a0, b0v[nn], acc[rh * 4 + nn], 0, 0, 0);
#pragma unroll
      for (int nn = 0; nn < 4; ++nn)
        acc[rh * 4 + nn] = __builtin_amdgcn_mfma_f32_16x16x32_bf16(a1, b1v[nn], acc[rh * 4 + nn], 0, 0, 0);
      __builtin_amdgcn_s_setprio(0);
      asm volatile("" ::: "memory");
      __builtin_amdgcn_s_barrier();
      if (t < 32) issue(48 + t);
    }
  }

  // ---- add(resid) + LN2 epilogue ----
  float x[8][4];
  float sums[4] = {0.f, 0.f, 0.f, 0.f}, sqs[4] = {0.f, 0.f, 0.f, 0.f};
#pragma unroll
  for (int m = 0; m < 8; ++m) {
    int col = ((m >> 2) << 7) + cbase + ((m & 3) << 5);
    float bs = b2[col];
#pragma unroll
    for (int q = 0; q < 4; ++q) {
      float v = acc[m][q] + bs + resid[m][q];
      x[m][q] = v;
      sums[q] += v;
      sqs[q] += v * v;
    }
  }
#pragma unroll
  for (int q = 0; q < 4; ++q) {
    sums[q] += __shfl_xor(sums[q], 1); sqs[q] += __shfl_xor(sqs[q], 1);
    sums[q] += __shfl_xor(sums[q], 2); sqs[q] += __shfl_xor(sqs[q], 2);
    sums[q] += __shfl_xor(sums[q], 4); sqs[q] += __shfl_xor(sqs[q], 4);
    sums[q] += __shfl_xor(sums[q], 8); sqs[q] += __shfl_xor(sqs[q], 8);
  }
  __syncthreads();
  if ((lane & 15) == 0) {
#pragma unroll
    for (int q = 0; q < 4; ++q) {
      red[wn][rowl + q][0] = sums[q];
      red[wn][rowl + q][1] = sqs[q];
    }
  }
  __syncthreads();
#pragma unroll
  for (int q = 0; q < 4; ++q) {
    float ts = sums[q] + red[wn ^ 1][rowl + q][0];
    float tq = sqs[q] + red[wn ^ 1][rowl + q][1];
    float mu = ts * (1.f / 256.f);
    float var = tq * (1.f / 256.f) - mu * mu;
    float rs = rsqrtf(var + 1e-5f);
    int row = bm + rowl + q;
#pragma unroll
    for (int m = 0; m < 8; ++m) {
      int col = ((m >> 2) << 7) + cbase + ((m & 3) << 5);
      float o = (x[m][q] - mu) * rs * g2[col] + lb2[col];
      src[(size_t)row * 256 + col] = o;
      sbo[(size_t)row * 256 + col] = f2bf(o);
    }
  }
}

// ---------------- fused conv0: NCHW f32 hint -> NHWC32 bf16 (SiLU) ----------------
__global__ __launch_bounds__(256) void k_conv0(
    const float* __restrict__ x, const float* __restrict__ w,
    unsigned short* __restrict__ y)
{
  __shared__ float ws[16][28];
  int tid = threadIdx.x;
  for (int u = tid; u < 432; u += 256) {
    int co = u / 27, k = u - co * 27;
    int t = k / 3, ci = k - t * 3;
    ws[co][k] = w[((size_t)co * 3 + ci) * 9 + t];
  }
  __syncthreads();
  int h = blockIdx.x, b = blockIdx.y, wo = tid;
  float xin[3][3][3];
#pragma unroll
  for (int ci = 0; ci < 3; ++ci)
#pragma unroll
    for (int kh = 0; kh < 3; ++kh) {
      int hi = h + kh - 1;
#pragma unroll
      for (int kw = 0; kw < 3; ++kw) {
        int wi = wo + kw - 1;
        xin[ci][kh][kw] = ((unsigned)hi < 256u && (unsigned)wi < 256u)
            ? x[(((size_t)b * 3 + ci) << 16) + (hi << 8) + wi] : 0.f;
      }
    }
  float acc[16] = {};
#pragma unroll
  for (int t = 0; t < 9; ++t) {
    const int kh = t / 3, kw = t % 3;
#pragma unroll
    for (int ci = 0; ci < 3; ++ci) {
      float xv = xin[ci][kh][kw];
#pragma unroll
      for (int co = 0; co < 16; ++co)
        acc[co] = fmaf(xv, ws[co][t * 3 + ci], acc[co]);
    }
  }
  us8v o0, o1, zv;
#pragma unroll
  for (int q = 0; q < 8; ++q) {
    float v0 = acc[q];     v0 = v0 / (1.f + __expf(-v0)); o0[q] = f2bf(v0);
    float v1 = acc[q + 8]; v1 = v1 / (1.f + __expf(-v1)); o1[q] = f2bf(v1);
    zv[q] = 0;
  }
  unsigned short* yp = y + ((((size_t)b << 16) + (h << 8) + wo) << 5);
  *(us8v*)(yp) = o0; *(us8v*)(yp + 8) = o1;
  *(us8v*)(yp + 16) = zv; *(us8v*)(yp + 24) = zv;
}

// ---------------- halo-LDS direct conv (Ci=32 NHWC, Co<=32, 3x3, pad 1, SiLU) ----
template<int S>
__global__ __launch_bounds__(256) void k_conv_direct(
    const unsigned short* __restrict__ x, const unsigned short* __restrict__ wp,
    int ldw, unsigned short* __restrict__ y, int Hi, int Ho, int Wo, int lwt)
{
  constexpr int HR = 7 * S + 3;
  constexpr int HC = 15 * S + 3;
  constexpr int HP = HR * HC;
  __shared__ unsigned short xs[HP * 40];
  __shared__ unsigned short wsh[32 * 312];
  int tid = threadIdx.x, lane = tid & 63, wv = tid >> 6;
  int b = blockIdx.y;
  int tr = blockIdx.x >> lwt, tc = blockIdx.x & ((1 << lwt) - 1);
  int hi0 = tr * 8 * S - 1, wi0 = tc * 16 * S - 1;

  for (int u = tid; u < HP * 8; u += 256) {
    int pix = u >> 3, part = u & 7;
    int hr = pix / HC, hcc = pix - hr * HC;
    int hi = hi0 + hr, wi = wi0 + hcc;
    ushort4 v = {0, 0, 0, 0};
    if ((unsigned)hi < (unsigned)Hi && (unsigned)wi < (unsigned)Hi)
      v = *(const ushort4*)(x + ((size_t)(b * Hi + hi) * Hi + wi) * 32 + part * 4);
    *(ushort4*)(&xs[pix * 40 + part * 4]) = v;
  }
  for (int u = tid; u < 2304; u += 256) {
    int co = u / 72, kk = (u - co * 72) * 4;
    *(ushort4*)(&wsh[co * 312 + kk]) = *(const ushort4*)(wp + (size_t)co * ldw + kk);
  }
  __syncthreads();

  int cL = lane & 15, kq = (lane >> 4) << 3;
  f32x4 acc[2][2];
#pragma unroll
  for (int m = 0; m < 2; ++m)
#pragma unroll
    for (int n = 0; n < 2; ++n)
#pragma unroll
      for (int q = 0; q < 4; ++q) acc[m][n][q] = 0.f;

#pragma unroll
  for (int tap = 0; tap < 9; ++tap) {
    const int kh = tap / 3, kw = tap % 3;
    bf16x8 af[2], bfr[2];
#pragma unroll
    for (int m = 0; m < 2; ++m) {
      int hr = (wv * 2 + m) * S + kh;
      int hc = cL * S + kw;
      af[m] = *(const bf16x8*)&xs[(hr * HC + hc) * 40 + kq];
    }
#pragma unroll
    for (int n = 0; n < 2; ++n)
      bfr[n] = *(const bf16x8*)&wsh[(cL + n * 16) * 312 + tap * 32 + kq];
#pragma unroll
    for (int m = 0; m < 2; ++m)
#pragma unroll
      for (int n = 0; n < 2; ++n)
        acc[m][n] = __builtin_amdgcn_mfma_f32_16x16x32_bf16(af[m], bfr[n], acc[m][n], 0, 0, 0);
  }

  int wo0 = tc * 16 + ((lane >> 4) << 2);
#pragma unroll
  for (int m = 0; m < 2; ++m) {
    int ho = tr * 8 + wv * 2 + m;
#pragma unroll
    for (int n = 0; n < 2; ++n) {
      int co = cL + n * 16;
#pragma unroll
      for (int q = 0; q < 4; ++q) {
        float v = acc[m][n][q];
        v = v / (1.f + __expf(-v));
        y[((size_t)(b * Ho + ho) * Wo + wo0 + q) * 32 + co] = f2bf(v);
      }
    }
  }
}

// ---------------- conv weight permute, all convs 1-7 in one launch ----------------
struct WP8 { const float* w[8]; unsigned short* q[8]; };
__global__ __launch_bounds__(256) void k_wperm_all(WP8 p)
{
  const int CoPs[8]  = {128, 32, 32, 32, 128, 128, 256, 256};
  const int CiRs[8]  = {3, 16, 16, 32, 32, 96, 96, 256};
  const int CiPs[8]  = {3, 32, 32, 32, 32, 96, 96, 256};
  const int Kpads[8] = {64, 288, 288, 288, 320, 896, 896, 2304};
  const int Cos[8]   = {16, 16, 32, 32, 96, 96, 256, 256};
  int i = blockIdx.y + 1;
  const float* w = p.w[i];
  unsigned short* wp = p.q[i];
  int Kpad = Kpads[i], CiP = CiPs[i], CiR = CiRs[i], Co = Cos[i];
  int total = CoPs[i] * Kpad;
  for (int idx = blockIdx.x * 256 + threadIdx.x; idx < total; idx += gridDim.x * 256) {
    int co = idx / Kpad, k = idx - co * Kpad;
    int t = k / CiP, ci = k - t * CiP;
    float v = 0.f;
    if (co < Co && t < 9 && ci < CiR) v = w[((size_t)co * CiR + ci) * 9 + t];
    wp[idx] = f2bf(v);
  }
}

// ---------------- merged prep: weight cvt/pad + pos table, 6 segments ----------
struct PrepArgs {
  const float *ipw, *outw, *l1w, *l2w, *l1b;
  unsigned short *wqkvb, *outwb, *l1wb, *l2wb, *posb;
  float *l1bp;
};
__global__ __launch_bounds__(256) void k_prep(PrepArgs a)
{
  int seg = blockIdx.y;
  int idx0 = blockIdx.x * 256 + threadIdx.x;
  int stride = gridDim.x * 256;
  if (seg == 0) {
    for (int i = idx0; i < 8 * 768 * 256; i += stride) a.wqkvb[i] = f2bf(a.ipw[i]);
  } else if (seg == 1) {
    for (int i = idx0; i < 8 * 256 * 256; i += stride) a.outwb[i] = f2bf(a.outw[i]);
  } else if (seg == 2) {
    for (int i = idx0; i < 8 * 1152 * 256; i += stride) {
      int l = i / (1152 * 256), r = (i >> 8) % 1152, c = i & 255;
      float v = (r < 1025) ? a.l1w[((size_t)l * 1025 + r) * 256 + c] : 0.f;
      a.l1wb[i] = f2bf(v);
    }
  } else if (seg == 3) {
    for (int i = idx0; i < 8 * 256 * 1152; i += stride) {
      int l = i / (256 * 1152), rc = i % (256 * 1152), r = rc / 1152, c = rc - (rc / 1152) * 1152;
      float v = (c < 1025) ? a.l2w[((size_t)l * 256 + r) * 1025 + c] : 0.f;
      a.l2wb[i] = f2bf(v);
    }
  } else if (seg == 4) {
    for (int i = idx0; i < 8 * 1152; i += stride) {
      int l = i / 1152, c = i - l * 1152;
      a.l1bp[i] = (c < 1025) ? a.l1b[l * 1025 + c] : 0.f;
    }
  } else {
    for (int i = idx0; i < 1024 * 256; i += stride) {
      int n = i >> 8, c = i & 255;
      int ih = n >> 5, iw = n & 31;
      float coord = (c < 128) ? (float)(ih + 1) : (float)(iw + 1);
      int cc = c & 127;
      float e = (float)((cc >> 1) << 1) * (1.f / 128.f);
      float t = coord / powf(10000.f, e);
      a.posb[i] = f2bf((cc & 1) ? cosf(t) : sinf(t));
    }
  }
}

// ---------------- neighborhood attention + next-layer weight L2 warming --------
__global__ __launch_bounds__(256) void k_attn(
    const unsigned short* __restrict__ qkv, unsigned short* __restrict__ ctx,
    const unsigned short* __restrict__ wwo, const unsigned short* __restrict__ ww1,
    const unsigned short* __restrict__ ww2)
{
  __shared__ unsigned short k_ldsu[848 * 8];
  __shared__ unsigned short v_lds[848 * 8];
  __shared__ float p_lds[64 * 50];
  int bx = blockIdx.x;
  int b = bx >> 4, tile = bx & 15;
  int th8 = ((tile >> 2) << 3), tw8 = ((tile & 3) << 3);
  int g = blockIdx.y;
  int tid = threadIdx.x, lane = tid & 63, wid = tid >> 6;
  int h0e = max(th8 - 3, 0), h1e = min(th8 + 10, 31);
  int w0e = max(tw8 - 3, 0), w1e = min(tw8 + 10, 31);
  int nh = h1e - h0e + 1, nw = w1e - w0e + 1;
  int nkeys = nh * nw, nslots = nkeys * 4;
  unsigned int magic = (65536u + (unsigned)nw - 1u) / (unsigned)nw;
  size_t qbase = (size_t)((unsigned)b << 10) * 768;

#pragma unroll
  for (int i = 0; i < 4; ++i) {
    int base = i * 256 + wid * 64;
    if (base < 784) {
      int s = min(base + lane, nslots - 1);
      int uidx = s >> 2, chunk = s & 3;
      int hh = (int)(((unsigned)uidx * magic) >> 16);
      int ww = uidx - hh * nw;
      hh += h0e; ww += w0e;
      const unsigned short* rp = qkv + qbase + (size_t)((hh << 5) + ww) * 768 + (g << 5) + chunk * 8;
      GLD16(rp + 256, &k_ldsu[base * 8]);
      GLD16(rp + 512, &v_lds[base * 8]);
    }
  }

  // ---- L2-warm next k_mlp weights: octets of linear block ids span the 8 XCDs,
  // each octet touches the same slice -> every XCD L2 gets every line. ----
  us8v wt[3];
  bool wvld[3] = {false, false, false};
  {
    int bid = bx + (g << 7);          // linear dispatch id (x-fastest)
    int slice = bid >> 3;             // 0..127: shared by ~one block per XCD
    const size_t TOT = 65536 + 294912 + 294912;   // wo + w1 + w2 (ushorts)
#pragma unroll
    for (int p = 0; p < 3; ++p) {
      size_t off = (size_t)slice * 5120 + (size_t)p * 2048 + (size_t)tid * 8;
      if (off < TOT) {
        const unsigned short* wp;
        if (off < 65536) wp = wwo + off;
        else if (off < 65536 + 294912) wp = ww1 + (off - 65536);
        else wp = ww2 + (off - 65536 - 294912);
        wt[p] = *(const us8v*)wp;
        wvld[p] = true;
      }
    }
  }
  __syncthreads();

  int q = tid >> 2, dq = tid & 3;
  int qh = th8 + (q >> 3), qw = tw8 + (q & 7);
  const float scale = 0.17677669529663687f;
  const unsigned short* qp = qkv + qbase + (size_t)((qh << 5) + qw) * 768 + (g << 5) + dq * 8;
  us8v uq = *(const us8v*)qp;
  float qr[8];
#pragma unroll
  for (int t = 0; t < 8; ++t) qr[t] = bf2f(uq[t]) * scale;

  int rbase[7], cofs[7];
  bool rval[7], cval[7];
#pragma unroll
  for (int d = 0; d < 7; ++d) {
    int mh = qh - 3 + d;
    rval[d] = (unsigned)mh < 32u;
    rbase[d] = (mh - h0e) * nw;
    int mw = qw - 3 + d;
    cval[d] = (unsigned)mw < 32u;
    cofs[d] = mw - w0e;
  }

  float m = -1e30f;
#pragma unroll
  for (int kk = 0; kk < 49; ++kk) {
    const int d7 = kk / 7, r7 = kk % 7;
    bool valid = rval[d7] && cval[r7];
    int uidx = valid ? (rbase[d7] + cofs[r7]) : 0;
    us8v uk = *(const us8v*)&k_ldsu[uidx * 32 + dq * 8];
    float d = 0.f;
#pragma unroll
    for (int t = 0; t < 8; ++t) d = fmaf(qr[t], bf2f(uk[t]), d);
    d += __shfl_xor(d, 1);
    d += __shfl_xor(d, 2);
    float s_kk = valid ? d : -1e30f;
    m = fmaxf(m, s_kk);
    if (dq == (kk & 3)) p_lds[q * 50 + kk] = s_kk;
  }
  float sum = 0.f;
  for (int kk = dq; kk < 49; kk += 4) {
    float e = __expf(p_lds[q * 50 + kk] - m);
    p_lds[q * 50 + kk] = e;
    sum += e;
  }
  sum += __shfl_xor(sum, 1);
  sum += __shfl_xor(sum, 2);
  float inv = 1.f / sum;

  float acc[8] = {};
#pragma unroll
  for (int kk = 0; kk < 49; ++kk) {
    const int d7 = kk / 7, r7 = kk % 7;
    int uidx = (rval[d7] && cval[r7]) ? (rbase[d7] + cofs[r7]) : 0;
    float pb = p_lds[q * 50 + kk];
    us8v uv = *(const us8v*)&v_lds[uidx * 32 + dq * 8];
#pragma unroll
    for (int t = 0; t < 8; ++t) acc[t] = fmaf(pb, bf2f(uv[t]), acc[t]);
  }
  unsigned short* op = ctx + ((size_t)((b << 10) + (qh << 5) + qw) << 8) + (g << 5) + dq * 8;
  us8v out;
#pragma unroll
  for (int t = 0; t < 8; ++t) out[t] = f2bf(acc[t] * inv);
  *(us8v*)op = out;

  // keep warming loads alive (prevents DCE; waits land here, post-compute)
#pragma unroll
  for (int p = 0; p < 3; ++p)
    if (wvld[p]) asm volatile("" :: "v"(wt[p]));
}

// ---------------- (B,1024,256) f32 -> (B,256,32,32) ----------------
__global__ void k_nxc_to_cxn(const float* __restrict__ x, float* __restrict__ y)
{
  __shared__ float t[32][33];
  int b = blockIdx.z;
  int c0 = blockIdx.x * 32, n0 = blockIdx.y * 32;
  int tx = threadIdx.x, ty = threadIdx.y;
  t[ty][tx] = x[((size_t)(b * 1024 + n0 + ty)) * 256 + c0 + tx];
  __syncthreads();
  y[((size_t)(b * 256 + c0 + ty)) * 1024 + n0 + tx] = t[tx][ty];
}

extern "C" void kernel_launch(void* const* d_in, const int* in_sizes, int n_in,
                              void* d_out, int out_size, void* d_ws, size_t ws_size,
                              hipStream_t stream)
{
  const float* hint = (const float*)d_in[0];
  const float* cw[8];
  for (int i = 0; i < 8; ++i) cw[i] = (const float*)d_in[1 + i];
  const float* ipw  = (const float*)d_in[9];
  const float* ipb  = (const float*)d_in[10];
  const float* outw = (const float*)d_in[11];
  const float* outb = (const float*)d_in[12];
  const float* l1w  = (const float*)d_in[13];
  const float* l1b  = (const float*)d_in[14];
  const float* l2w  = (const float*)d_in[15];
  const float* l2b  = (const float*)d_in[16];
  const float* g1   = (const float*)d_in[17];
  const float* b1   = (const float*)d_in[18];
  const float* g2   = (const float*)d_in[19];
  const float* b2   = (const float*)d_in[20];

  float* ws = (float*)d_ws;
  size_t off = 0;
  float* bufA = ws + off; off += 8388608;
  float* bufB = ws + off; off += 8388608;
  float* src  = ws + off; off += 2097152;
  unsigned short* srcb = (unsigned short*)(ws + off); off += 1048576;
  unsigned short* posb = (unsigned short*)(ws + off); off += 131072;
  float* posqk = ws + off; off += 4194304;
  unsigned short* wqkvb = (unsigned short*)(ws + off); off += 786432;
  unsigned short* outwb = (unsigned short*)(ws + off); off += 262144;
  unsigned short* l1wb  = (unsigned short*)(ws + off); off += 1179648;
  unsigned short* l2wb  = (unsigned short*)(ws + off); off += 1179648;
  float* l1bp = ws + off; off += 9216;
  unsigned short* cwp[8];
  const int CoPs[8]  = {128, 32, 32, 32, 128, 128, 256, 256};
  const int Kpads[8] = {64, 288, 288, 288, 320, 896, 896, 2304};
  for (int i = 0; i < 8; ++i) { cwp[i] = (unsigned short*)(ws + off); off += ((size_t)CoPs[i] * Kpads[i] + 1) / 2; }
  unsigned short* zpage = (unsigned short*)(ws + off); off += 64;

  hipMemsetAsync(zpage, 0, 256, stream);

  // ---- prep ----
  PrepArgs pa;
  pa.ipw = ipw; pa.outw = outw; pa.l1w = l1w; pa.l2w = l2w; pa.l1b = l1b;
  pa.wqkvb = wqkvb; pa.outwb = outwb; pa.l1wb = l1wb; pa.l2wb = l2wb;
  pa.posb = posb; pa.l1bp = l1bp;
  k_prep<<<dim3(256, 6), 256, 0, stream>>>(pa);
  WP8 wpargs;
  for (int i = 0; i < 8; ++i) { wpargs.w[i] = cw[i]; wpargs.q[i] = cwp[i]; }
  k_wperm_all<<<dim3(64, 7), 256, 0, stream>>>(wpargs);

  unsigned short* bufAu = (unsigned short*)bufA;
  unsigned short* bufBu = (unsigned short*)bufB;

#define GEMM_TAIL nullptr, 0, 0, 0, 0, 0, 0, nullptr, nullptr
  // ---- conv stack ----
  k_conv0<<<dim3(256, 8), 256, 0, stream>>>(hint, cw[0], bufAu);
  k_conv_direct<1><<<dim3(512, 8), 256, 0, stream>>>(bufAu, cwp[1], 288, bufBu, 256, 256, 256, 4);
  k_conv_direct<2><<<dim3(128, 8), 256, 0, stream>>>(bufBu, cwp[2], 288, bufAu, 256, 128, 128, 3);
  k_conv_direct<1><<<dim3(128, 8), 256, 0, stream>>>(bufAu, cwp[3], 288, bufBu, 128, 128, 128, 3);
  k_gemm<128, 128, 512, 1, 0, 5><<<dim3(256, 1), 512, 0, stream>>>(   // conv4
      bufBu, 0, cwp[4], 320, nullptr, nullptr, nullptr, bufAu, 96, 320, 96, 2, 1,
      0, 0, zpage, 32, 128, 2, 6, 1, 0, nullptr, nullptr);
  k_gemm<128, 128, 512, 1, 0, 14><<<dim3(256, 1), 512, 0, stream>>>(  // conv5
      bufAu, 0, cwp[5], 896, nullptr, nullptr, nullptr, bufBu, 96, 896, 96, 2, 1,
      0, 0, zpage, 96, 64, 1, 6, 171, 9, nullptr, nullptr);
  k_gemm<64, 128, 512, 1, 0, 14><<<dim3(128, 2), 512, 0, stream>>>(   // conv6
      bufBu, 0, cwp[6], 896, nullptr, nullptr, nullptr, bufAu, 256, 896, 256, 2, 1,
      0, 0, zpage, 96, 64, 2, 5, 171, 9, nullptr, nullptr);
  k_gemm<64, 128, 512, 1><<<dim3(128, 2), 512, 0, stream>>>(          // conv7
      bufAu, 0, cwp[7], 2304, nullptr, nullptr, src, srcb, 256, 2304, 256, 0, 2,
      0, 0, zpage, 256, 32, 1, 5, 1, 3, nullptr, nullptr);

  // ---- posqk[l] = pos @ [Wq;Wk]^T, batched over 8 layers ----
  k_gemm<64, 128, 512, 0, 0, 4><<<dim3(16, 4, 8), 512, 0, stream>>>(
      posb, 256, wqkvb, 256, nullptr, nullptr, posqk, nullptr, 512, 256, 512, 0, 0,
      196608LL, 524288LL, GEMM_TAIL);

  unsigned short* qkvb = bufAu;
  unsigned short* ctx  = (unsigned short*)(bufA + 3145728);

  // ---- transformer layers ----
  for (int l = 0; l < 8; ++l) {
    const unsigned short* wqkv_l = wqkvb + (size_t)l * 768 * 256;
    const float* ipb_l  = ipb  + (size_t)l * 768;
    const unsigned short* outw_l = outwb + (size_t)l * 256 * 256;
    const float* outb_l = outb + (size_t)l * 256;
    const unsigned short* l1w_l = l1wb + (size_t)l * 1152 * 256;
    const float* l1b_l  = l1bp + (size_t)l * 1152;
    const unsigned short* l2w_l = l2wb + (size_t)l * 256 * 1152;
    const float* l2b_l  = l2b  + (size_t)l * 256;
    const float* posqk_l = posqk + (size_t)l * 524288;
    const float* g1_l = g1 + l * 256; const float* b1_l = b1 + l * 256;
    const float* g2_l = g2 + l * 256; const float* b2_l = b2 + l * 256;

    k_gemm<64, 128, 512, 0, 0, 4><<<dim3(128, 6), 512, 0, stream>>>(   // QKV
        srcb, 256, wqkv_l, 256, ipb_l, posqk_l, nullptr, qkvb, 768, 256, 768, 0, 1,
        0, 0, GEMM_TAIL);
    k_attn<<<dim3(128, 8), 256, 0, stream>>>(qkvb, ctx, outw_l, l1w_l, l2w_l);
    k_mlp<<<dim3(256), 256, 0, stream>>>(
        ctx, outw_l, outb_l, l1w_l, l1b_l, l2w_l, l2b_l,
        src, srcb, g1_l, b1_l, g2_l, b2_l);
  }

  // ---- output ----
  k_nxc_to_cxn<<<dim3(8, 32, 8), dim3(32, 32), 0, stream>>>(src, (float*)d_out);
}